// Round 8
// baseline (193.855 us; speedup 1.0000x reference)
//
#include <hip/hip_runtime.h>
#include <hip/hip_bf16.h>

// RetrieverBase: q[64][32][128] f32, p[128][180][128] f32
// out = concat(term_relevance[64][128][32][180], query_maxsim[64][128][32], relevance[64][128])
#define A_N 64
#define B_N 128
#define Q_N 32
#define D_N 180
#define V_N 128

typedef __attribute__((ext_vector_type(8))) short bf16x8;   // 8 bf16 (4 VGPRs)
typedef __attribute__((ext_vector_type(4))) float f32x4;

__device__ __forceinline__ short f2bf(float f) {
  __hip_bfloat16 h = __float2bfloat16(f);
  return (short)__builtin_bit_cast(unsigned short, h);
}

__device__ __forceinline__ bf16x8 pack8(const f32x4& lo, const f32x4& hi) {
  bf16x8 v;
  v[0] = f2bf(lo[0]); v[1] = f2bf(lo[1]); v[2] = f2bf(lo[2]); v[3] = f2bf(lo[3]);
  v[4] = f2bf(hi[0]); v[5] = f2bf(hi[1]); v[6] = f2bf(hi[2]); v[7] = f2bf(hi[3]);
  return v;
}

// R7 hit 3.5 TB/s; the harness fill kernel proves 6.7-6.9 TB/s write BW with
// full-line stores. Gap = our 16B stores at 720B row stride touch 64 lines
// per instr (partial). This version stages each C[32x180] in LDS and streams
// it out as FULL 64B lines (1KB/instr ascending, fill-pattern), double-
// buffered so stores of pair i-1 fly UNDER compute of pair i (one barrier
// per pair -- avoids R5's drain-burst serialization).
//
// Grid 1024 = 8 ag x 128 b, b FAST: bid%8==b%8 keeps each XCD's p slice
// (16 passages, 1.5MB) L2-resident. Block = 768 thr = 12 waves, one b.
// Wave wv owns d-tile dt=wv for ALL 8 pairs: its p-fragments (16 VGPR) are
// loaded from global ONCE per block. Per pair: 8 MFMA -> ds_write C-subtile
// -> barrier; next iteration stores the finished buffer cooperatively.
// LDS = 2x23040 (cbuf) + smax = ~49KB -> 2 blocks/CU (24 waves, VGPR<=84
// via launch_bounds(768,6) and qt-sequenced compute).
__global__ __launch_bounds__(768, 6) void score_kernel(
    const float* __restrict__ q, const float* __restrict__ p,
    float* __restrict__ out) {
  const int bid  = blockIdx.x;
  const int b    = bid & (B_N - 1);
  const int ag   = bid >> 7;          // 0..7 -> a = ag*8 + i
  const int tid  = threadIdx.x;
  const int wv   = tid >> 6;          // 0..11 == d-tile
  const int lane = tid & 63;
  const int l16  = lane & 15;
  const int g    = lane >> 4;         // 0..3

  __shared__ float cbuf[2][Q_N * D_N];   // 2 x 23040 B
  __shared__ float smax[2][12][Q_N];     // 3072 B

  // ---- this wave's p-fragments: loaded once, reused for all 8 pairs ----
  // A[row=d-in-tile][k]; lane supplies p-row (wv*16 + l16), k = kk*32+g*8..+7
  const float* __restrict__ pb = p + (size_t)b * D_N * V_N;
  const int drow = wv * 16 + l16;
  const int dr   = drow < D_N ? drow : (D_N - 1);   // tail clamp (max-safe dups)
  bf16x8 pf[4];
#pragma unroll
  for (int kk = 0; kk < 4; ++kk) {
    const float* s = pb + (size_t)dr * V_N + kk * 32 + g * 8;
    pf[kk] = pack8(*reinterpret_cast<const f32x4*>(s),
                   *reinterpret_cast<const f32x4*>(s + 4));
  }

  const size_t TERM_SZ = (size_t)A_N * B_N * Q_N * D_N;
  const size_t MS_SZ   = (size_t)A_N * B_N * Q_N;
  const int d0 = wv * 16 + g * 4;     // lane's 4 consecutive d columns

  // 9 iterations: compute pair i (i<8) AFTER issuing stores of pair i-1 (i>0).
  for (int i = 0; i <= 8; ++i) {
    // ---- store phase: stream pair i-1's C from LDS as full lines ----
    if (i > 0) {
      const int ap = ag * 8 + (i - 1);
      const float* cb = cbuf[(i - 1) & 1];
      const size_t outbase = ((size_t)ap * B_N + b) * (size_t)(Q_N * D_N);
      // 1440 x 16B chunks over 768 threads: ascending, 64B-aligned region
#pragma unroll
      for (int c = tid; c < Q_N * D_N / 4; c += 768)
        *reinterpret_cast<f32x4*>(out + outbase + (size_t)c * 4) =
            *reinterpret_cast<const f32x4*>(&cb[c * 4]);

      if (tid < Q_N) {   // finalize maxsim + relevance for pair i-1
        const float (*sm)[Q_N] = smax[(i - 1) & 1];
        float m = sm[0][tid];
#pragma unroll
        for (int w = 1; w < 12; ++w) m = fmaxf(m, sm[w][tid]);
        out[TERM_SZ + ((size_t)ap * B_N + b) * Q_N + tid] = m;
        float s = m;
        s += __shfl_xor(s, 1, 64);
        s += __shfl_xor(s, 2, 64);
        s += __shfl_xor(s, 4, 64);
        s += __shfl_xor(s, 8, 64);
        s += __shfl_xor(s, 16, 64);
        if (tid == 0)
          out[TERM_SZ + MS_SZ + (size_t)ap * B_N + b] = s;
      }
    }

    // ---- compute phase: pair i into cbuf[i&1] ----
    if (i < 8) {
      const int a = ag * 8 + i;
      const float* __restrict__ qa = q + (size_t)a * Q_N * V_N;
      float* cb = cbuf[i & 1];

#pragma unroll
      for (int qt = 0; qt < 2; ++qt) {   // sequenced q-halves keep VGPR low
        // B-fragments: B[k][col=q]; lane reads q[qt*16+l16][kk*32+g*8..+7]
        bf16x8 qf[4];
#pragma unroll
        for (int kk = 0; kk < 4; ++kk) {
          const float* s = qa + (size_t)(qt * 16 + l16) * V_N + kk * 32 + g * 8;
          qf[kk] = pack8(*reinterpret_cast<const f32x4*>(s),
                         *reinterpret_cast<const f32x4*>(s + 4));
        }

        f32x4 acc = (f32x4){0.f, 0.f, 0.f, 0.f};
#pragma unroll
        for (int kk = 0; kk < 4; ++kk)
          acc = __builtin_amdgcn_mfma_f32_16x16x32_bf16(pf[kk], qf[kk], acc, 0, 0, 0);

        // C/D layout: col=l16=q, row=g*4+reg=d-in-tile
        float qm = fmaxf(fmaxf(acc[0], acc[1]), fmaxf(acc[2], acc[3]));
        if (d0 < D_N)   // only dt==11, g>0 masked (clamped dup rows)
          *reinterpret_cast<f32x4*>(&cb[(qt * 16 + l16) * D_N + d0]) = acc;

        // per-q max across the 4 g-groups
        qm = fmaxf(qm, __shfl_xor(qm, 16, 64));
        qm = fmaxf(qm, __shfl_xor(qm, 32, 64));
        if (lane < 16) smax[i & 1][wv][qt * 16 + lane] = qm;
      }
    }

    __syncthreads();   // one barrier per pair: cbuf[i&1] ready; prev reads done
  }
}

extern "C" void kernel_launch(void* const* d_in, const int* in_sizes, int n_in,
                              void* d_out, int out_size, void* d_ws, size_t ws_size,
                              hipStream_t stream) {
  const float* q = (const float*)d_in[0];
  const float* p = (const float*)d_in[1];
  float* out = (float*)d_out;
  dim3 grid(1024);   // 8 a-groups x 128 b (b fast -> XCD-stable p residency)
  dim3 block(768);   // 12 waves: wave = d-tile; 8 (a,b) pairs per block
  hipLaunchKernelGGL(score_kernel, grid, block, 0, stream, q, p, out);
}